// Round 13
// baseline (2680.045 us; speedup 1.0000x reference)
//
#include <hip/hip_runtime.h>
#include <cstdint>
#include <cstddef>

#define BS 8
#define TT 256
#define DD 2048
#define NN 8192
#define KK 64
#define GG 512
#define GSZ 16
#define HH 64
#define MIN_ 69
#define MOUT_ 66
#define NSL 32     // slices per batch
#define SLN 256    // neurons per slice
#define NW (NN/2)  // packed words per batch (4096)

typedef float    f32x4 __attribute__((ext_vector_type(4)));
typedef uint32_t u32x4 __attribute__((ext_vector_type(4)));

// ---------------- Phase 0a: initial bank schedule (sorted + stride-2) -------
// One wave per neuron (lane = orig position k). Stable-sort the 64 neighbor
// indices by PACKED-WORD LDS bank ((idx>>1)&31), rotation stride 2 (R11).
// Entry carries orig position k in bits 16+ for the repair/inv2 rebuild:
//   ad_stored[n][j] = (k<<16) | (word byte-offset) | (idx&1)
__global__ __launch_bounds__(256) void prep_kernel(
    const int* __restrict__ conn, int* __restrict__ ad_stored)
{
  const int gtid = blockIdx.x * 256 + threadIdx.x;
  const int n    = gtid >> 6;
  const int k    = gtid & 63;
  int idx  = conn[(size_t)n * KK + k];
  int bank = (idx >> 1) & 31;
  unsigned key = ((unsigned)bank << 6) | (unsigned)k;
  int rank = 0;
  #pragma unroll
  for (int i = 0; i < 64; ++i) {
    unsigned ki = (unsigned)__shfl((int)key, i);
    rank += (ki < key) ? 1 : 0;
  }
  const int ln = n & 63;
  const int r  = ((ln & 31) * 2 + (ln >> 5)) & 63;
  int j = (rank - r) & 63;
  ad_stored[(size_t)n * KK + j] = (k << 16) | ((idx >> 1) << 2) | (idx & 1);
}

// ---------------- Phase 0b: joint per-wave conflict repair ------------------
// One 64-thread WG per scan wave-group (64 consecutive neurons that share a
// hardware wave in scan_kernel; lane l = neuron base+l). E[j][l] = lane l's
// entry for round j (LDS, conflict-free access). H[j][b] = #lanes hitting
// bank b in round j. Greedy repair passes: lane with overloaded (j,b) swaps
// its round-j and round-j2 entries when the swap removes one overload unit
// and creates none (H kept exact via LDS atomics; stale-read races only cost
// quality, never correctness — any per-lane permutation is valid since inv2
// is rebuilt from the carried k afterward).
__global__ __launch_bounds__(64) void repair_kernel(
    int* __restrict__ ad_stored, unsigned char* __restrict__ inv2)
{
  const int l = threadIdx.x;
  const int n = blockIdx.x * 64 + l;
  __shared__ int E[64][64];   // [round][lane]
  __shared__ int H[64][32];   // [round][bank]

  for (int j = 0; j < 64; ++j) E[j][l] = ad_stored[(size_t)n * KK + j];
  for (int i = l; i < 64 * 32; i += 64) (&H[0][0])[i] = 0;
  __syncthreads();
  for (int j = 0; j < 64; ++j)
    atomicAdd(&H[j][(E[j][l] >> 2) & 31], 1);
  __syncthreads();

  for (int pass = 0; pass < 3; ++pass) {
    for (int j = 0; j < 64; ++j) {
      int e  = E[j][l];
      int b  = (e >> 2) & 31;
      if (H[j][b] > 2) {
        for (int d = 1; d < 64; ++d) {
          int j2 = (j + d) & 63;
          int e2 = E[j2][l];
          int b2 = (e2 >> 2) & 31;
          if (b2 != b && H[j2][b] <= 1 && H[j][b2] <= 1) {
            atomicSub(&H[j][b], 1);  atomicAdd(&H[j2][b], 1);
            atomicSub(&H[j2][b2], 1); atomicAdd(&H[j][b2], 1);
            E[j][l] = e2; E[j2][l] = e;
            break;
          }
        }
      }
    }
    __syncthreads();
  }

  // write back schedule + rebuild weight permutation
  for (int j = 0; j < 64; ++j) {
    int e = E[j][l];
    ad_stored[(size_t)n * KK + j] = e & 0xFFFF;
    inv2[(size_t)n * KK + (e >> 16)] = (unsigned char)j;
  }
}

// ---------------- Phase A: modulator (runs once) ----------------
// One WG per group; weights staged in LDS once, batches looped. o<KK outputs
// written PRE-PERMUTED via inv2 so scan's straight vector load of wconn pairs
// element j with ad_stored[n][j].
__global__ __launch_bounds__(256) void modulator_kernel(
    const float* __restrict__ w1, const float* __restrict__ b1,
    const float* __restrict__ w2, const float* __restrict__ b2,
    const float* __restrict__ act0, const float* __restrict__ heb0,
    const float* __restrict__ dec0, const float* __restrict__ thr0,
    const float* __restrict__ nid, const unsigned char* __restrict__ inv2,
    float* __restrict__ wconn, float* __restrict__ decayB, float* __restrict__ thrB)
{
  const int g = blockIdx.x, tid = threadIdx.x;
  __shared__ float w1s[MIN_ * HH];
  __shared__ float w2s[HH * MOUT_];
  __shared__ float b2s[MOUT_];
  __shared__ float xs[GSZ][MIN_];
  __shared__ float hd[GSZ * HH];

  for (int j = tid; j < MIN_ * HH; j += 256) w1s[j] = w1[(size_t)g * MIN_ * HH + j];
  for (int j = tid; j < HH * MOUT_; j += 256) w2s[j] = w2[(size_t)g * HH * MOUT_ + j];
  if (tid < MOUT_) b2s[tid] = b2[g * MOUT_ + tid];
  const float b1v = b1[g * HH + (tid & 63)];
  const int nbase = g * GSZ;

  for (int b = 0; b < BS; ++b) {
    __syncthreads();
    for (int j = tid; j < GSZ * KK; j += 256) {
      int s = j >> 6, k = j & 63;
      xs[s][1 + k] = heb0[((size_t)(b * NN + nbase + s)) * KK + k];
    }
    if (tid < GSZ) {
      int n = nbase + tid;
      xs[tid][0]  = act0[b * NN + n];
      xs[tid][65] = dec0[b * NN + n];
      xs[tid][66] = thr0[b * NN + n];
      xs[tid][67] = nid[2 * n];
      xs[tid][68] = nid[2 * n + 1];
    }
    __syncthreads();

    #pragma unroll
    for (int rep = 0; rep < 4; ++rep) {
      int s = rep * 4 + (tid >> 6), h = tid & 63;
      float acc = b1v;
      for (int i = 0; i < MIN_; ++i) acc = fmaf(xs[s][i], w1s[i * HH + h], acc);
      hd[s * HH + h] = tanhf(acc);
    }
    __syncthreads();

    for (int j = tid; j < GSZ * MOUT_; j += 256) {
      int s = j / MOUT_, o = j - s * MOUT_;
      float acc = b2s[o];
      for (int h = 0; h < HH; ++h) acc = fmaf(hd[s * HH + h], w2s[h * MOUT_ + o], acc);
      int nn = nbase + s;
      int gidx = b * NN + nn;
      if (o < KK) {
        int jp = inv2[(size_t)nn * KK + o];
        wconn[(size_t)gidx * KK + jp] = acc;
      }
      else if (o == KK) decayB[gidx] = 1.f / (1.f + expf(-acc));
      else              thrB[gidx]   = acc;
    }
  }
}

// ---------------- Phase B: 256-step recurrent scan (R12, unchanged) --------
// Exchange word: [tag8 | act12(odd) | act12(even)] — two neurons per dword.
// Data IS the flag; reload-as-poll on the 16KB coherent reload; sc0 sc1.
// WAR safety: R6 induction unchanged.
__global__ __launch_bounds__(256, 1) void scan_kernel(
    const float* __restrict__ cc, const int* __restrict__ ad_stored,
    const float* __restrict__ V0, const float* __restrict__ act0,
    const float* __restrict__ wconn, const float* __restrict__ decayB,
    const float* __restrict__ thrB,
    float* __restrict__ out, uint32_t* actbuf)
{
  const int tid = threadIdx.x;
  const int b   = blockIdx.x & 7;
  const int sl  = blockIdx.x >> 3;
  const int n    = sl * SLN + tid;
  const int gidx = b * NN + n;

  __shared__ uint32_t alds[NW];     // 16 KB: packed acts of batch b

  f32x4 w4[16];
  int   ad[KK];
  uint32_t mlo = 0, mhi = 0;
  {
    const f32x4* wr = reinterpret_cast<const f32x4*>(wconn + (size_t)gidx * KK);
    #pragma unroll
    for (int j = 0; j < 16; ++j) {
      f32x4 v = wr[j];
      w4[j] = v * (1.f / 4095.f);
    }
    const int4* ir = reinterpret_cast<const int4*>(ad_stored + (size_t)n * KK);
    #pragma unroll
    for (int j = 0; j < KK / 4; ++j) {
      int4 v = ir[j];
      ad[4*j+0] = v.x; ad[4*j+1] = v.y;
      ad[4*j+2] = v.z; ad[4*j+3] = v.w;
    }
    #pragma unroll
    for (int k = 0; k < 32; ++k) { mlo |= (uint32_t)(ad[k] & 1) << k;      ad[k] &= ~1; }
    #pragma unroll
    for (int k = 32; k < 64; ++k) { mhi |= (uint32_t)(ad[k] & 1) << (k-32); ad[k] &= ~1; }
  }
  float V     = V0[gidx];
  float dec   = decayB[gidx];
  float onemd = 1.f - dec;
  float thr   = thrB[gidx];

  // initial act into LDS, packed to the same 12-bit format
  for (int w = tid; w < NW; w += 256) {
    float a0 = act0[(size_t)b * NN + 2 * w];
    float a1 = act0[(size_t)b * NN + 2 * w + 1];
    uint32_t q0 = (uint32_t)__builtin_rintf(a0 * 4095.f);
    uint32_t q1 = (uint32_t)__builtin_rintf(a1 * 4095.f);
    alds[w] = (q1 << 12) | q0;
  }
  __syncthreads();

  float inj = cc[((size_t)b * TT) * DD + (n >> 2)];
  const char* abase = reinterpret_cast<const char*>(alds);

  for (int t = 0; t < TT; ++t) {
    float s0 = 0.f, s1 = 0.f, s2 = 0.f, s3 = 0.f;
    #pragma unroll
    for (int j = 0; j < 16; ++j) {
      uint32_t d0 = *reinterpret_cast<const uint32_t*>(abase + ad[4*j+0]);
      uint32_t d1 = *reinterpret_cast<const uint32_t*>(abase + ad[4*j+1]);
      uint32_t d2 = *reinterpret_cast<const uint32_t*>(abase + ad[4*j+2]);
      uint32_t d3 = *reinterpret_cast<const uint32_t*>(abase + ad[4*j+3]);
      uint32_t sh0, sh1, sh2, sh3;
      if (4*j+3 < 32) {
        sh0 = ((mlo >> (4*j+0)) & 1) * 12; sh1 = ((mlo >> (4*j+1)) & 1) * 12;
        sh2 = ((mlo >> (4*j+2)) & 1) * 12; sh3 = ((mlo >> (4*j+3)) & 1) * 12;
      } else {
        sh0 = ((mhi >> (4*j+0-32)) & 1) * 12; sh1 = ((mhi >> (4*j+1-32)) & 1) * 12;
        sh2 = ((mhi >> (4*j+2-32)) & 1) * 12; sh3 = ((mhi >> (4*j+3-32)) & 1) * 12;
      }
      s0 = fmaf((float)((d0 >> sh0) & 0xFFFu), w4[j].x, s0);
      s1 = fmaf((float)((d1 >> sh1) & 0xFFFu), w4[j].y, s1);
      s2 = fmaf((float)((d2 >> sh2) & 0xFFFu), w4[j].z, s2);
      s3 = fmaf((float)((d3 >> sh3) & 0xFFFu), w4[j].w, s3);
    }
    float recv = (s0 + s1) + (s2 + s3) + inj;
    V = dec * V + onemd * recv;
    float x = V - thr;
    float a = 1.f / (1.f + expf(-x));

    const int pw = t & 1;

    if (t != TT - 1) {
      uint32_t aq = (uint32_t)__builtin_rintf(a * 4095.f);
      uint32_t oq = (uint32_t)__shfl_xor((int)aq, 1);
      if ((tid & 1) == 0) {
        uint32_t word = ((uint32_t)(t + 1) << 24) | (oq << 12) | aq;
        uint32_t* dst = actbuf + (size_t)pw * (BS * NW) + (gidx >> 1);
        asm volatile("global_store_dword %0, %1, off sc0 sc1"
                     :: "v"(dst), "v"(word) : "memory");
      }
    }

    float p = a + __shfl_xor(a, 1);
    p = p + __shfl_xor(p, 2);
    if ((tid & 3) == 0)
      out[((size_t)b * TT + t) * DD + sl * 64 + (tid >> 2)] = 0.25f * p;

    if (t == TT - 1) break;

    inj = cc[((size_t)b * TT + t + 1) * DD + (n >> 2)];

    const uint32_t* src = actbuf + (size_t)pw * (BS * NW) + (size_t)b * NW;
    const uint32_t tag = (uint32_t)(t + 1);
    u32x4 vals[4];
    for (;;) {
      #pragma unroll
      for (int j = 0; j < 4; ++j) {
        const uint32_t* p4 = src + (tid << 2) + (j << 10);
        asm volatile("global_load_dwordx4 %0, %1, off sc0 sc1"
                     : "=v"(vals[j]) : "v"(p4));
      }
      asm volatile("s_waitcnt vmcnt(0)" ::: "memory");
      uint32_t bad = 0;
      #pragma unroll
      for (int j = 0; j < 4; ++j) {
        bad |= (vals[j].x >> 24) ^ tag;
        bad |= (vals[j].y >> 24) ^ tag;
        bad |= (vals[j].z >> 24) ^ tag;
        bad |= (vals[j].w >> 24) ^ tag;
      }
      if (bad == 0) break;
    }
    {
      u32x4* dst = reinterpret_cast<u32x4*>(alds);
      #pragma unroll
      for (int j = 0; j < 4; ++j) dst[tid + j * 256] = vals[j];
    }
    __syncthreads();
  }
}

extern "C" void kernel_launch(void* const* d_in, const int* in_sizes, int n_in,
                              void* d_out, int out_size, void* d_ws, size_t ws_size,
                              hipStream_t stream)
{
  const float* cc   = (const float*)d_in[0];
  const float* w1   = (const float*)d_in[1];
  const float* b1   = (const float*)d_in[2];
  const float* w2   = (const float*)d_in[3];
  const float* b2   = (const float*)d_in[4];
  const int*   conn = (const int*)d_in[5];
  const float* nid  = (const float*)d_in[6];
  const float* V0   = (const float*)d_in[7];
  const float* act0 = (const float*)d_in[8];
  const float* heb0 = (const float*)d_in[9];
  const float* dec0 = (const float*)d_in[10];
  const float* thr0 = (const float*)d_in[11];
  float* out = (float*)d_out;

  char* ws = (char*)d_ws;
  float*         wconn  = (float*)ws;                                   // 16 MB
  float*         decayB = (float*)(ws + (size_t)BS * NN * KK * 4);      // 256 KB
  float*         thrB   = decayB + BS * NN;                             // 256 KB
  uint32_t*      actbuf = (uint32_t*)(thrB + BS * NN);                  // 2*8*4096 dw
  int*           ad_st  = (int*)(actbuf + 2 * BS * NW);                 // 2 MB
  unsigned char* inv2   = (unsigned char*)(ad_st + (size_t)NN * KK);    // 512 KB

  // zero tags every launch (replay-deterministic; first poll expects tag 1)
  hipMemsetAsync(actbuf, 0, 2 * BS * NW * sizeof(uint32_t), stream);

  prep_kernel<<<dim3(NN * KK / 256), 256, 0, stream>>>(conn, ad_st);
  repair_kernel<<<dim3(NN / 64), 64, 0, stream>>>(ad_st, inv2);
  modulator_kernel<<<dim3(GG), 256, 0, stream>>>(w1, b1, w2, b2, act0, heb0, dec0,
                                                 thr0, nid, inv2, wconn, decayB, thrB);
  scan_kernel<<<dim3(BS * NSL), 256, 0, stream>>>(cc, ad_st, V0, act0, wconn,
                                                  decayB, thrB, out, actbuf);
}

// Round 14
// 1029.403 us; speedup vs baseline: 2.6035x; 2.6035x over previous
//
#include <hip/hip_runtime.h>
#include <cstdint>
#include <cstddef>

#define BS 8
#define TT 256
#define DD 2048
#define NN 8192
#define KK 64
#define GG 512
#define GSZ 16
#define HH 64
#define MIN_ 69
#define MOUT_ 66
#define NSL 32     // slices per batch
#define SLN 256    // neurons per slice
#define NW (NN/2)  // packed words per batch (4096)

typedef float    f32x4 __attribute__((ext_vector_type(4)));
typedef uint32_t u32x4 __attribute__((ext_vector_type(4)));

// ---------------- Phase 0a: initial bank schedule (sorted + stride-2) -------
// One wave per neuron (lane = orig position k). Stable-sort the 64 neighbor
// indices by PACKED-WORD LDS bank ((idx>>1)&31), rotation stride 2 (R11).
// Entry carries orig position k in bits 16+ for the repair/inv2 rebuild:
//   ad_stored[n][j] = (k<<16) | (word byte-offset) | (idx&1)
__global__ __launch_bounds__(256) void prep_kernel(
    const int* __restrict__ conn, int* __restrict__ ad_stored)
{
  const int gtid = blockIdx.x * 256 + threadIdx.x;
  const int n    = gtid >> 6;
  const int k    = gtid & 63;
  int idx  = conn[(size_t)n * KK + k];
  int bank = (idx >> 1) & 31;
  unsigned key = ((unsigned)bank << 6) | (unsigned)k;
  int rank = 0;
  #pragma unroll
  for (int i = 0; i < 64; ++i) {
    unsigned ki = (unsigned)__shfl((int)key, i);
    rank += (ki < key) ? 1 : 0;
  }
  const int ln = n & 63;
  const int r  = ((ln & 31) * 2 + (ln >> 5)) & 63;
  int j = (rank - r) & 63;
  ad_stored[(size_t)n * KK + j] = (k << 16) | ((idx >> 1) << 2) | (idx & 1);
}

// ---------------- Phase 0b: joint repair v2 — deficit-mask bounded probe ----
// One 64-thread WG per scan wave-group. E[j][l] = lane l's round-j entry.
// H[j][b] exact histogram (LDS atomics). M[b] = 64-bit mask of rounds where
// H[j][b] <= 1 (deficit), rebuilt between passes, read stale within a pass.
// Per round j: lanes with H[j][b] > 2 claim mover status (atomicSub, restore
// if not truly overloaded), probe <=8 deficit rounds from ctz(M[b]), recheck
// H fresh, commit swap with exact atomics. Races cost quality only; any
// per-lane permutation is correct (inv2 rebuilt from carried k — R13-proven).
__global__ __launch_bounds__(64) void repair_kernel(
    int* __restrict__ ad_stored, unsigned char* __restrict__ inv2)
{
  const int l = threadIdx.x;
  const int n = blockIdx.x * 64 + l;
  __shared__ int E[64][64];                 // [round][lane]
  __shared__ int H[64][32];                 // [round][bank]
  __shared__ unsigned long long M[32];      // deficit masks per bank

  for (int j = 0; j < 64; ++j) E[j][l] = ad_stored[(size_t)n * KK + j];
  for (int i = l; i < 64 * 32; i += 64) (&H[0][0])[i] = 0;
  __syncthreads();
  for (int j = 0; j < 64; ++j)
    atomicAdd(&H[j][(E[j][l] >> 2) & 31], 1);
  __syncthreads();

  for (int pass = 0; pass < 2; ++pass) {
    // (re)build deficit masks: threads 0..31, one bank each
    if (l < 32) {
      unsigned long long m = 0;
      for (int j = 0; j < 64; ++j)
        if (H[j][l] <= 1) m |= 1ull << j;
      M[l] = m;
    }
    __syncthreads();

    for (int j = 0; j < 64; ++j) {
      int e = E[j][l];
      int b = (e >> 2) & 31;
      if (H[j][b] > 2) {                       // cheap read-first guard
        int old = atomicSub(&H[j][b], 1);
        if (old > 2) {                         // claimed mover
          unsigned long long m = M[b] & ~(1ull << j);
          bool placed = false;
          int probes = 0;
          while (m && probes < 8) {
            int j2 = __builtin_ctzll(m); m &= m - 1; ++probes;
            int e2 = E[j2][l];
            int b2 = (e2 >> 2) & 31;
            if (b2 != b && H[j2][b] <= 1 && H[j][b2] <= 1) {
              atomicAdd(&H[j2][b], 1);
              atomicSub(&H[j2][b2], 1);
              atomicAdd(&H[j][b2], 1);
              E[j][l] = e2; E[j2][l] = e;
              placed = true;
              break;
            }
          }
          if (!placed) atomicAdd(&H[j][b], 1); // restore
        } else {
          atomicAdd(&H[j][b], 1);              // restore (not overloaded)
        }
      }
    }
    __syncthreads();
  }

  // write back schedule + rebuild weight permutation
  for (int j = 0; j < 64; ++j) {
    int e = E[j][l];
    ad_stored[(size_t)n * KK + j] = e & 0xFFFF;
    inv2[(size_t)n * KK + (e >> 16)] = (unsigned char)j;
  }
}

// ---------------- Phase A: modulator (runs once) ----------------
// One WG per group; weights staged in LDS once, batches looped. o<KK outputs
// written PRE-PERMUTED via inv2 so scan's straight vector load of wconn pairs
// element j with ad_stored[n][j].
__global__ __launch_bounds__(256) void modulator_kernel(
    const float* __restrict__ w1, const float* __restrict__ b1,
    const float* __restrict__ w2, const float* __restrict__ b2,
    const float* __restrict__ act0, const float* __restrict__ heb0,
    const float* __restrict__ dec0, const float* __restrict__ thr0,
    const float* __restrict__ nid, const unsigned char* __restrict__ inv2,
    float* __restrict__ wconn, float* __restrict__ decayB, float* __restrict__ thrB)
{
  const int g = blockIdx.x, tid = threadIdx.x;
  __shared__ float w1s[MIN_ * HH];
  __shared__ float w2s[HH * MOUT_];
  __shared__ float b2s[MOUT_];
  __shared__ float xs[GSZ][MIN_];
  __shared__ float hd[GSZ * HH];

  for (int j = tid; j < MIN_ * HH; j += 256) w1s[j] = w1[(size_t)g * MIN_ * HH + j];
  for (int j = tid; j < HH * MOUT_; j += 256) w2s[j] = w2[(size_t)g * HH * MOUT_ + j];
  if (tid < MOUT_) b2s[tid] = b2[g * MOUT_ + tid];
  const float b1v = b1[g * HH + (tid & 63)];
  const int nbase = g * GSZ;

  for (int b = 0; b < BS; ++b) {
    __syncthreads();
    for (int j = tid; j < GSZ * KK; j += 256) {
      int s = j >> 6, k = j & 63;
      xs[s][1 + k] = heb0[((size_t)(b * NN + nbase + s)) * KK + k];
    }
    if (tid < GSZ) {
      int n = nbase + tid;
      xs[tid][0]  = act0[b * NN + n];
      xs[tid][65] = dec0[b * NN + n];
      xs[tid][66] = thr0[b * NN + n];
      xs[tid][67] = nid[2 * n];
      xs[tid][68] = nid[2 * n + 1];
    }
    __syncthreads();

    #pragma unroll
    for (int rep = 0; rep < 4; ++rep) {
      int s = rep * 4 + (tid >> 6), h = tid & 63;
      float acc = b1v;
      for (int i = 0; i < MIN_; ++i) acc = fmaf(xs[s][i], w1s[i * HH + h], acc);
      hd[s * HH + h] = tanhf(acc);
    }
    __syncthreads();

    for (int j = tid; j < GSZ * MOUT_; j += 256) {
      int s = j / MOUT_, o = j - s * MOUT_;
      float acc = b2s[o];
      for (int h = 0; h < HH; ++h) acc = fmaf(hd[s * HH + h], w2s[h * MOUT_ + o], acc);
      int nn = nbase + s;
      int gidx = b * NN + nn;
      if (o < KK) {
        int jp = inv2[(size_t)nn * KK + o];
        wconn[(size_t)gidx * KK + jp] = acc;
      }
      else if (o == KK) decayB[gidx] = 1.f / (1.f + expf(-acc));
      else              thrB[gidx]   = acc;
    }
  }
}

// ---------------- Phase B: 256-step recurrent scan (R12, unchanged) --------
// Exchange word: [tag8 | act12(odd) | act12(even)] — two neurons per dword.
// Data IS the flag; reload-as-poll on the 16KB coherent reload; sc0 sc1.
// WAR safety: R6 induction unchanged.
__global__ __launch_bounds__(256, 1) void scan_kernel(
    const float* __restrict__ cc, const int* __restrict__ ad_stored,
    const float* __restrict__ V0, const float* __restrict__ act0,
    const float* __restrict__ wconn, const float* __restrict__ decayB,
    const float* __restrict__ thrB,
    float* __restrict__ out, uint32_t* actbuf)
{
  const int tid = threadIdx.x;
  const int b   = blockIdx.x & 7;
  const int sl  = blockIdx.x >> 3;
  const int n    = sl * SLN + tid;
  const int gidx = b * NN + n;

  __shared__ uint32_t alds[NW];     // 16 KB: packed acts of batch b

  f32x4 w4[16];
  int   ad[KK];
  uint32_t mlo = 0, mhi = 0;
  {
    const f32x4* wr = reinterpret_cast<const f32x4*>(wconn + (size_t)gidx * KK);
    #pragma unroll
    for (int j = 0; j < 16; ++j) {
      f32x4 v = wr[j];
      w4[j] = v * (1.f / 4095.f);
    }
    const int4* ir = reinterpret_cast<const int4*>(ad_stored + (size_t)n * KK);
    #pragma unroll
    for (int j = 0; j < KK / 4; ++j) {
      int4 v = ir[j];
      ad[4*j+0] = v.x; ad[4*j+1] = v.y;
      ad[4*j+2] = v.z; ad[4*j+3] = v.w;
    }
    #pragma unroll
    for (int k = 0; k < 32; ++k) { mlo |= (uint32_t)(ad[k] & 1) << k;      ad[k] &= ~1; }
    #pragma unroll
    for (int k = 32; k < 64; ++k) { mhi |= (uint32_t)(ad[k] & 1) << (k-32); ad[k] &= ~1; }
  }
  float V     = V0[gidx];
  float dec   = decayB[gidx];
  float onemd = 1.f - dec;
  float thr   = thrB[gidx];

  // initial act into LDS, packed to the same 12-bit format
  for (int w = tid; w < NW; w += 256) {
    float a0 = act0[(size_t)b * NN + 2 * w];
    float a1 = act0[(size_t)b * NN + 2 * w + 1];
    uint32_t q0 = (uint32_t)__builtin_rintf(a0 * 4095.f);
    uint32_t q1 = (uint32_t)__builtin_rintf(a1 * 4095.f);
    alds[w] = (q1 << 12) | q0;
  }
  __syncthreads();

  float inj = cc[((size_t)b * TT) * DD + (n >> 2)];
  const char* abase = reinterpret_cast<const char*>(alds);

  for (int t = 0; t < TT; ++t) {
    float s0 = 0.f, s1 = 0.f, s2 = 0.f, s3 = 0.f;
    #pragma unroll
    for (int j = 0; j < 16; ++j) {
      uint32_t d0 = *reinterpret_cast<const uint32_t*>(abase + ad[4*j+0]);
      uint32_t d1 = *reinterpret_cast<const uint32_t*>(abase + ad[4*j+1]);
      uint32_t d2 = *reinterpret_cast<const uint32_t*>(abase + ad[4*j+2]);
      uint32_t d3 = *reinterpret_cast<const uint32_t*>(abase + ad[4*j+3]);
      uint32_t sh0, sh1, sh2, sh3;
      if (4*j+3 < 32) {
        sh0 = ((mlo >> (4*j+0)) & 1) * 12; sh1 = ((mlo >> (4*j+1)) & 1) * 12;
        sh2 = ((mlo >> (4*j+2)) & 1) * 12; sh3 = ((mlo >> (4*j+3)) & 1) * 12;
      } else {
        sh0 = ((mhi >> (4*j+0-32)) & 1) * 12; sh1 = ((mhi >> (4*j+1-32)) & 1) * 12;
        sh2 = ((mhi >> (4*j+2-32)) & 1) * 12; sh3 = ((mhi >> (4*j+3-32)) & 1) * 12;
      }
      s0 = fmaf((float)((d0 >> sh0) & 0xFFFu), w4[j].x, s0);
      s1 = fmaf((float)((d1 >> sh1) & 0xFFFu), w4[j].y, s1);
      s2 = fmaf((float)((d2 >> sh2) & 0xFFFu), w4[j].z, s2);
      s3 = fmaf((float)((d3 >> sh3) & 0xFFFu), w4[j].w, s3);
    }
    float recv = (s0 + s1) + (s2 + s3) + inj;
    V = dec * V + onemd * recv;
    float x = V - thr;
    float a = 1.f / (1.f + expf(-x));

    const int pw = t & 1;

    if (t != TT - 1) {
      uint32_t aq = (uint32_t)__builtin_rintf(a * 4095.f);
      uint32_t oq = (uint32_t)__shfl_xor((int)aq, 1);
      if ((tid & 1) == 0) {
        uint32_t word = ((uint32_t)(t + 1) << 24) | (oq << 12) | aq;
        uint32_t* dst = actbuf + (size_t)pw * (BS * NW) + (gidx >> 1);
        asm volatile("global_store_dword %0, %1, off sc0 sc1"
                     :: "v"(dst), "v"(word) : "memory");
      }
    }

    float p = a + __shfl_xor(a, 1);
    p = p + __shfl_xor(p, 2);
    if ((tid & 3) == 0)
      out[((size_t)b * TT + t) * DD + sl * 64 + (tid >> 2)] = 0.25f * p;

    if (t == TT - 1) break;

    inj = cc[((size_t)b * TT + t + 1) * DD + (n >> 2)];

    const uint32_t* src = actbuf + (size_t)pw * (BS * NW) + (size_t)b * NW;
    const uint32_t tag = (uint32_t)(t + 1);
    u32x4 vals[4];
    for (;;) {
      #pragma unroll
      for (int j = 0; j < 4; ++j) {
        const uint32_t* p4 = src + (tid << 2) + (j << 10);
        asm volatile("global_load_dwordx4 %0, %1, off sc0 sc1"
                     : "=v"(vals[j]) : "v"(p4));
      }
      asm volatile("s_waitcnt vmcnt(0)" ::: "memory");
      uint32_t bad = 0;
      #pragma unroll
      for (int j = 0; j < 4; ++j) {
        bad |= (vals[j].x >> 24) ^ tag;
        bad |= (vals[j].y >> 24) ^ tag;
        bad |= (vals[j].z >> 24) ^ tag;
        bad |= (vals[j].w >> 24) ^ tag;
      }
      if (bad == 0) break;
    }
    {
      u32x4* dst = reinterpret_cast<u32x4*>(alds);
      #pragma unroll
      for (int j = 0; j < 4; ++j) dst[tid + j * 256] = vals[j];
    }
    __syncthreads();
  }
}

extern "C" void kernel_launch(void* const* d_in, const int* in_sizes, int n_in,
                              void* d_out, int out_size, void* d_ws, size_t ws_size,
                              hipStream_t stream)
{
  const float* cc   = (const float*)d_in[0];
  const float* w1   = (const float*)d_in[1];
  const float* b1   = (const float*)d_in[2];
  const float* w2   = (const float*)d_in[3];
  const float* b2   = (const float*)d_in[4];
  const int*   conn = (const int*)d_in[5];
  const float* nid  = (const float*)d_in[6];
  const float* V0   = (const float*)d_in[7];
  const float* act0 = (const float*)d_in[8];
  const float* heb0 = (const float*)d_in[9];
  const float* dec0 = (const float*)d_in[10];
  const float* thr0 = (const float*)d_in[11];
  float* out = (float*)d_out;

  char* ws = (char*)d_ws;
  float*         wconn  = (float*)ws;                                   // 16 MB
  float*         decayB = (float*)(ws + (size_t)BS * NN * KK * 4);      // 256 KB
  float*         thrB   = decayB + BS * NN;                             // 256 KB
  uint32_t*      actbuf = (uint32_t*)(thrB + BS * NN);                  // 2*8*4096 dw
  int*           ad_st  = (int*)(actbuf + 2 * BS * NW);                 // 2 MB
  unsigned char* inv2   = (unsigned char*)(ad_st + (size_t)NN * KK);    // 512 KB

  // zero tags every launch (replay-deterministic; first poll expects tag 1)
  hipMemsetAsync(actbuf, 0, 2 * BS * NW * sizeof(uint32_t), stream);

  prep_kernel<<<dim3(NN * KK / 256), 256, 0, stream>>>(conn, ad_st);
  repair_kernel<<<dim3(NN / 64), 64, 0, stream>>>(ad_st, inv2);
  modulator_kernel<<<dim3(GG), 256, 0, stream>>>(w1, b1, w2, b2, act0, heb0, dec0,
                                                 thr0, nid, inv2, wconn, decayB, thrB);
  scan_kernel<<<dim3(BS * NSL), 256, 0, stream>>>(cc, ad_st, V0, act0, wconn,
                                                  decayB, thrB, out, actbuf);
}

// Round 15
// 850.331 us; speedup vs baseline: 3.1518x; 1.2106x over previous
//
#include <hip/hip_runtime.h>
#include <cstdint>
#include <cstddef>

#define BS 8
#define TT 256
#define DD 2048
#define NN 8192
#define KK 64
#define GG 512
#define GSZ 16
#define HH 64
#define MIN_ 69
#define MOUT_ 66
#define NSL 32     // slices per batch
#define SLN 256    // neurons per slice
#define NW (NN/2)  // packed words per batch (4096)

typedef float    f32x4 __attribute__((ext_vector_type(4)));
typedef uint32_t u32x4 __attribute__((ext_vector_type(4)));

// ---------------- Phase 0: bank schedule (sorted + stride-2, R12) -----------
// One wave per neuron (lane = orig position k). Stable-sort the 64 neighbor
// indices by PACKED-WORD LDS bank ((idx>>1)&31), rotation stride 2 (R11):
// in round j a 32-lane phase reads sorted positions {j+2l} -> banks
// ~(j/2+l) mod 32 = all 32 banks once per phase. Writes:
//   ad_stored[n][j] = (word byte-offset) | (idx&1)   [bit0 = 12-bit field sel]
//   inv2[n][k]      = round position of orig neighbor k (weight permutation)
__global__ __launch_bounds__(256) void prep_kernel(
    const int* __restrict__ conn, int* __restrict__ ad_stored,
    unsigned char* __restrict__ inv2)
{
  const int gtid = blockIdx.x * 256 + threadIdx.x;
  const int n    = gtid >> 6;
  const int lane = gtid & 63;
  int idx  = conn[(size_t)n * KK + lane];
  int bank = (idx >> 1) & 31;
  unsigned key = ((unsigned)bank << 6) | (unsigned)lane;
  int rank = 0;
  #pragma unroll
  for (int i = 0; i < 64; ++i) {
    unsigned ki = (unsigned)__shfl((int)key, i);
    rank += (ki < key) ? 1 : 0;
  }
  const int ln = n & 63;                             // hw lane of neuron n in scan
  const int r  = ((ln & 31) * 2 + (ln >> 5)) & 63;   // stride-2 de-phasing
  int j = (rank - r) & 63;
  ad_stored[(size_t)n * KK + j] = ((idx >> 1) << 2) | (idx & 1);
  inv2[(size_t)n * KK + lane]   = (unsigned char)j;
}

// ---------------- Phase A: modulator (runs once) ----------------
// One WG per group; weights staged in LDS once, batches looped. o<KK outputs
// written PRE-PERMUTED via inv2 so scan's straight vector load of wconn pairs
// element j with ad_stored[n][j].
__global__ __launch_bounds__(256) void modulator_kernel(
    const float* __restrict__ w1, const float* __restrict__ b1,
    const float* __restrict__ w2, const float* __restrict__ b2,
    const float* __restrict__ act0, const float* __restrict__ heb0,
    const float* __restrict__ dec0, const float* __restrict__ thr0,
    const float* __restrict__ nid, const unsigned char* __restrict__ inv2,
    float* __restrict__ wconn, float* __restrict__ decayB, float* __restrict__ thrB)
{
  const int g = blockIdx.x, tid = threadIdx.x;
  __shared__ float w1s[MIN_ * HH];
  __shared__ float w2s[HH * MOUT_];
  __shared__ float b2s[MOUT_];
  __shared__ float xs[GSZ][MIN_];
  __shared__ float hd[GSZ * HH];

  for (int j = tid; j < MIN_ * HH; j += 256) w1s[j] = w1[(size_t)g * MIN_ * HH + j];
  for (int j = tid; j < HH * MOUT_; j += 256) w2s[j] = w2[(size_t)g * HH * MOUT_ + j];
  if (tid < MOUT_) b2s[tid] = b2[g * MOUT_ + tid];
  const float b1v = b1[g * HH + (tid & 63)];
  const int nbase = g * GSZ;

  for (int b = 0; b < BS; ++b) {
    __syncthreads();
    for (int j = tid; j < GSZ * KK; j += 256) {
      int s = j >> 6, k = j & 63;
      xs[s][1 + k] = heb0[((size_t)(b * NN + nbase + s)) * KK + k];
    }
    if (tid < GSZ) {
      int n = nbase + tid;
      xs[tid][0]  = act0[b * NN + n];
      xs[tid][65] = dec0[b * NN + n];
      xs[tid][66] = thr0[b * NN + n];
      xs[tid][67] = nid[2 * n];
      xs[tid][68] = nid[2 * n + 1];
    }
    __syncthreads();

    #pragma unroll
    for (int rep = 0; rep < 4; ++rep) {
      int s = rep * 4 + (tid >> 6), h = tid & 63;
      float acc = b1v;
      for (int i = 0; i < MIN_; ++i) acc = fmaf(xs[s][i], w1s[i * HH + h], acc);
      hd[s * HH + h] = tanhf(acc);
    }
    __syncthreads();

    for (int j = tid; j < GSZ * MOUT_; j += 256) {
      int s = j / MOUT_, o = j - s * MOUT_;
      float acc = b2s[o];
      for (int h = 0; h < HH; ++h) acc = fmaf(hd[s * HH + h], w2s[h * MOUT_ + o], acc);
      int nn = nbase + s;
      int gidx = b * NN + nn;
      if (o < KK) {
        int jp = inv2[(size_t)nn * KK + o];
        wconn[(size_t)gidx * KK + jp] = acc;
      }
      else if (o == KK) decayB[gidx] = 1.f / (1.f + expf(-acc));
      else              thrB[gidx]   = acc;
    }
  }
}

// ---------------- Phase B: 256-step recurrent scan (R12 + hybrid poll) -----
// Exchange word: [tag8 | act12(odd) | act12(even)] — two neurons per dword.
// Data IS the flag; reload-as-poll on the 16KB coherent reload.
// R15 HYBRID POLL: publish store stays sc0 sc1 (proven). Reload attempts
// 0..1 use sc0-ONLY loads — if the sc1 write-through leaves the line live in
// the writer's XCD L2 (batch=blk&7 co-locates all 32 WGs per XCD), detection
// + data arrive at L2 latency. Attempts >=2 use the PROVEN sc0 sc1 path.
// Correctness/liveness NEVER depend on sc0 visibility: every word is
// tag-verified (stale => retry), and the bounded fallback guarantees progress
// (R5's mistake — liveness gambled on unverified semantics — is not repeated).
// WAR safety: R6 induction unchanged (verified reload precedes t+2 publish).
__global__ __launch_bounds__(256, 1) void scan_kernel(
    const float* __restrict__ cc, const int* __restrict__ ad_stored,
    const float* __restrict__ V0, const float* __restrict__ act0,
    const float* __restrict__ wconn, const float* __restrict__ decayB,
    const float* __restrict__ thrB,
    float* __restrict__ out, uint32_t* actbuf)
{
  const int tid = threadIdx.x;
  const int b   = blockIdx.x & 7;
  const int sl  = blockIdx.x >> 3;
  const int n    = sl * SLN + tid;
  const int gidx = b * NN + n;

  __shared__ uint32_t alds[NW];     // 16 KB: packed acts of batch b

  f32x4 w4[16];
  int   ad[KK];
  uint32_t mlo = 0, mhi = 0;
  {
    const f32x4* wr = reinterpret_cast<const f32x4*>(wconn + (size_t)gidx * KK);
    #pragma unroll
    for (int j = 0; j < 16; ++j) {
      f32x4 v = wr[j];
      w4[j] = v * (1.f / 4095.f);
    }
    const int4* ir = reinterpret_cast<const int4*>(ad_stored + (size_t)n * KK);
    #pragma unroll
    for (int j = 0; j < KK / 4; ++j) {
      int4 v = ir[j];
      ad[4*j+0] = v.x; ad[4*j+1] = v.y;
      ad[4*j+2] = v.z; ad[4*j+3] = v.w;
    }
    #pragma unroll
    for (int k = 0; k < 32; ++k) { mlo |= (uint32_t)(ad[k] & 1) << k;      ad[k] &= ~1; }
    #pragma unroll
    for (int k = 32; k < 64; ++k) { mhi |= (uint32_t)(ad[k] & 1) << (k-32); ad[k] &= ~1; }
  }
  float V     = V0[gidx];
  float dec   = decayB[gidx];
  float onemd = 1.f - dec;
  float thr   = thrB[gidx];

  // initial act into LDS, packed to the same 12-bit format
  for (int w = tid; w < NW; w += 256) {
    float a0 = act0[(size_t)b * NN + 2 * w];
    float a1 = act0[(size_t)b * NN + 2 * w + 1];
    uint32_t q0 = (uint32_t)__builtin_rintf(a0 * 4095.f);
    uint32_t q1 = (uint32_t)__builtin_rintf(a1 * 4095.f);
    alds[w] = (q1 << 12) | q0;
  }
  __syncthreads();

  float inj = cc[((size_t)b * TT) * DD + (n >> 2)];
  const char* abase = reinterpret_cast<const char*>(alds);

  for (int t = 0; t < TT; ++t) {
    float s0 = 0.f, s1 = 0.f, s2 = 0.f, s3 = 0.f;
    #pragma unroll
    for (int j = 0; j < 16; ++j) {
      uint32_t d0 = *reinterpret_cast<const uint32_t*>(abase + ad[4*j+0]);
      uint32_t d1 = *reinterpret_cast<const uint32_t*>(abase + ad[4*j+1]);
      uint32_t d2 = *reinterpret_cast<const uint32_t*>(abase + ad[4*j+2]);
      uint32_t d3 = *reinterpret_cast<const uint32_t*>(abase + ad[4*j+3]);
      uint32_t sh0, sh1, sh2, sh3;
      if (4*j+3 < 32) {
        sh0 = ((mlo >> (4*j+0)) & 1) * 12; sh1 = ((mlo >> (4*j+1)) & 1) * 12;
        sh2 = ((mlo >> (4*j+2)) & 1) * 12; sh3 = ((mlo >> (4*j+3)) & 1) * 12;
      } else {
        sh0 = ((mhi >> (4*j+0-32)) & 1) * 12; sh1 = ((mhi >> (4*j+1-32)) & 1) * 12;
        sh2 = ((mhi >> (4*j+2-32)) & 1) * 12; sh3 = ((mhi >> (4*j+3-32)) & 1) * 12;
      }
      s0 = fmaf((float)((d0 >> sh0) & 0xFFFu), w4[j].x, s0);
      s1 = fmaf((float)((d1 >> sh1) & 0xFFFu), w4[j].y, s1);
      s2 = fmaf((float)((d2 >> sh2) & 0xFFFu), w4[j].z, s2);
      s3 = fmaf((float)((d3 >> sh3) & 0xFFFu), w4[j].w, s3);
    }
    float recv = (s0 + s1) + (s2 + s3) + inj;
    V = dec * V + onemd * recv;
    float x = V - thr;
    float a = 1.f / (1.f + expf(-x));

    const int pw = t & 1;

    if (t != TT - 1) {
      uint32_t aq = (uint32_t)__builtin_rintf(a * 4095.f);
      uint32_t oq = (uint32_t)__shfl_xor((int)aq, 1);
      if ((tid & 1) == 0) {
        uint32_t word = ((uint32_t)(t + 1) << 24) | (oq << 12) | aq;
        uint32_t* dst = actbuf + (size_t)pw * (BS * NW) + (gidx >> 1);
        asm volatile("global_store_dword %0, %1, off sc0 sc1"
                     :: "v"(dst), "v"(word) : "memory");
      }
    }

    float p = a + __shfl_xor(a, 1);
    p = p + __shfl_xor(p, 2);
    if ((tid & 3) == 0)
      out[((size_t)b * TT + t) * DD + sl * 64 + (tid >> 2)] = 0.25f * p;

    if (t == TT - 1) break;

    inj = cc[((size_t)b * TT + t + 1) * DD + (n >> 2)];

    // hybrid reload-as-poll: attempts 0-1 sc0-only (XCD-L2 fast path),
    // attempts >=2 sc0 sc1 (proven device-coherent fallback)
    const uint32_t* src = actbuf + (size_t)pw * (BS * NW) + (size_t)b * NW;
    const uint32_t tag = (uint32_t)(t + 1);
    u32x4 vals[4];
    int att = 0;
    for (;;) {
      if (att < 2) {
        #pragma unroll
        for (int j = 0; j < 4; ++j) {
          const uint32_t* p4 = src + (tid << 2) + (j << 10);
          asm volatile("global_load_dwordx4 %0, %1, off sc0"
                       : "=v"(vals[j]) : "v"(p4));
        }
      } else {
        #pragma unroll
        for (int j = 0; j < 4; ++j) {
          const uint32_t* p4 = src + (tid << 2) + (j << 10);
          asm volatile("global_load_dwordx4 %0, %1, off sc0 sc1"
                       : "=v"(vals[j]) : "v"(p4));
        }
      }
      asm volatile("s_waitcnt vmcnt(0)" ::: "memory");
      uint32_t bad = 0;
      #pragma unroll
      for (int j = 0; j < 4; ++j) {
        bad |= (vals[j].x >> 24) ^ tag;
        bad |= (vals[j].y >> 24) ^ tag;
        bad |= (vals[j].z >> 24) ^ tag;
        bad |= (vals[j].w >> 24) ^ tag;
      }
      if (bad == 0) break;
      ++att;
    }
    {
      u32x4* dst = reinterpret_cast<u32x4*>(alds);
      #pragma unroll
      for (int j = 0; j < 4; ++j) dst[tid + j * 256] = vals[j];
    }
    __syncthreads();
  }
}

extern "C" void kernel_launch(void* const* d_in, const int* in_sizes, int n_in,
                              void* d_out, int out_size, void* d_ws, size_t ws_size,
                              hipStream_t stream)
{
  const float* cc   = (const float*)d_in[0];
  const float* w1   = (const float*)d_in[1];
  const float* b1   = (const float*)d_in[2];
  const float* w2   = (const float*)d_in[3];
  const float* b2   = (const float*)d_in[4];
  const int*   conn = (const int*)d_in[5];
  const float* nid  = (const float*)d_in[6];
  const float* V0   = (const float*)d_in[7];
  const float* act0 = (const float*)d_in[8];
  const float* heb0 = (const float*)d_in[9];
  const float* dec0 = (const float*)d_in[10];
  const float* thr0 = (const float*)d_in[11];
  float* out = (float*)d_out;

  char* ws = (char*)d_ws;
  float*         wconn  = (float*)ws;                                   // 16 MB
  float*         decayB = (float*)(ws + (size_t)BS * NN * KK * 4);      // 256 KB
  float*         thrB   = decayB + BS * NN;                             // 256 KB
  uint32_t*      actbuf = (uint32_t*)(thrB + BS * NN);                  // 2*8*4096 dw
  int*           ad_st  = (int*)(actbuf + 2 * BS * NW);                 // 2 MB
  unsigned char* inv2   = (unsigned char*)(ad_st + (size_t)NN * KK);    // 512 KB

  // zero tags every launch (replay-deterministic; first poll expects tag 1)
  hipMemsetAsync(actbuf, 0, 2 * BS * NW * sizeof(uint32_t), stream);

  prep_kernel<<<dim3(NN * KK / 256), 256, 0, stream>>>(conn, ad_st, inv2);
  modulator_kernel<<<dim3(GG), 256, 0, stream>>>(w1, b1, w2, b2, act0, heb0, dec0,
                                                 thr0, nid, inv2, wconn, decayB, thrB);
  scan_kernel<<<dim3(BS * NSL), 256, 0, stream>>>(cc, ad_st, V0, act0, wconn,
                                                  decayB, thrB, out, actbuf);
}

// Round 16
// 774.478 us; speedup vs baseline: 3.4605x; 1.0979x over previous
//
#include <hip/hip_runtime.h>
#include <cstdint>
#include <cstddef>

#define BS 8
#define TT 256
#define DD 2048
#define NN 8192
#define KK 64
#define GG 512
#define GSZ 16
#define HH 64
#define MIN_ 69
#define MOUT_ 66
#define NSL 32     // slices per batch
#define SLN 256    // neurons per slice
#define NW (NN/2)  // packed words per batch (4096)

typedef float    f32x4 __attribute__((ext_vector_type(4)));
typedef uint32_t u32x4 __attribute__((ext_vector_type(4)));

// ---------------- Phase 0: bank schedule (sorted + stride-2, R12) -----------
// One wave per neuron (lane = orig position k). Stable-sort the 64 neighbor
// indices by PACKED-WORD LDS bank ((idx>>1)&31), rotation stride 2 (R11):
// in round j a 32-lane phase reads sorted positions {j+2l} -> banks
// ~(j/2+l) mod 32 = all 32 banks once per phase. Writes:
//   ad_stored[n][j] = (word byte-offset) | (idx&1)   [bit0 = 12-bit field sel]
//   inv2[n][k]      = round position of orig neighbor k (weight permutation)
__global__ __launch_bounds__(256) void prep_kernel(
    const int* __restrict__ conn, int* __restrict__ ad_stored,
    unsigned char* __restrict__ inv2)
{
  const int gtid = blockIdx.x * 256 + threadIdx.x;
  const int n    = gtid >> 6;
  const int lane = gtid & 63;
  int idx  = conn[(size_t)n * KK + lane];
  int bank = (idx >> 1) & 31;
  unsigned key = ((unsigned)bank << 6) | (unsigned)lane;
  int rank = 0;
  #pragma unroll
  for (int i = 0; i < 64; ++i) {
    unsigned ki = (unsigned)__shfl((int)key, i);
    rank += (ki < key) ? 1 : 0;
  }
  const int ln = n & 63;                             // hw lane of neuron n in scan
  const int r  = ((ln & 31) * 2 + (ln >> 5)) & 63;   // stride-2 de-phasing
  int j = (rank - r) & 63;
  ad_stored[(size_t)n * KK + j] = ((idx >> 1) << 2) | (idx & 1);
  inv2[(size_t)n * KK + lane]   = (unsigned char)j;
}

// ---------------- Phase A: modulator (runs once) ----------------
// One WG per group; weights staged in LDS once, batches looped. o<KK outputs
// written PRE-PERMUTED via inv2 so scan's straight vector load of wconn pairs
// element j with ad_stored[n][j].
__global__ __launch_bounds__(256) void modulator_kernel(
    const float* __restrict__ w1, const float* __restrict__ b1,
    const float* __restrict__ w2, const float* __restrict__ b2,
    const float* __restrict__ act0, const float* __restrict__ heb0,
    const float* __restrict__ dec0, const float* __restrict__ thr0,
    const float* __restrict__ nid, const unsigned char* __restrict__ inv2,
    float* __restrict__ wconn, float* __restrict__ decayB, float* __restrict__ thrB)
{
  const int g = blockIdx.x, tid = threadIdx.x;
  __shared__ float w1s[MIN_ * HH];
  __shared__ float w2s[HH * MOUT_];
  __shared__ float b2s[MOUT_];
  __shared__ float xs[GSZ][MIN_];
  __shared__ float hd[GSZ * HH];

  for (int j = tid; j < MIN_ * HH; j += 256) w1s[j] = w1[(size_t)g * MIN_ * HH + j];
  for (int j = tid; j < HH * MOUT_; j += 256) w2s[j] = w2[(size_t)g * HH * MOUT_ + j];
  if (tid < MOUT_) b2s[tid] = b2[g * MOUT_ + tid];
  const float b1v = b1[g * HH + (tid & 63)];
  const int nbase = g * GSZ;

  for (int b = 0; b < BS; ++b) {
    __syncthreads();
    for (int j = tid; j < GSZ * KK; j += 256) {
      int s = j >> 6, k = j & 63;
      xs[s][1 + k] = heb0[((size_t)(b * NN + nbase + s)) * KK + k];
    }
    if (tid < GSZ) {
      int n = nbase + tid;
      xs[tid][0]  = act0[b * NN + n];
      xs[tid][65] = dec0[b * NN + n];
      xs[tid][66] = thr0[b * NN + n];
      xs[tid][67] = nid[2 * n];
      xs[tid][68] = nid[2 * n + 1];
    }
    __syncthreads();

    #pragma unroll
    for (int rep = 0; rep < 4; ++rep) {
      int s = rep * 4 + (tid >> 6), h = tid & 63;
      float acc = b1v;
      for (int i = 0; i < MIN_; ++i) acc = fmaf(xs[s][i], w1s[i * HH + h], acc);
      hd[s * HH + h] = tanhf(acc);
    }
    __syncthreads();

    for (int j = tid; j < GSZ * MOUT_; j += 256) {
      int s = j / MOUT_, o = j - s * MOUT_;
      float acc = b2s[o];
      for (int h = 0; h < HH; ++h) acc = fmaf(hd[s * HH + h], w2s[h * MOUT_ + o], acc);
      int nn = nbase + s;
      int gidx = b * NN + nn;
      if (o < KK) {
        int jp = inv2[(size_t)nn * KK + o];
        wconn[(size_t)gidx * KK + jp] = acc;
      }
      else if (o == KK) decayB[gidx] = 1.f / (1.f + expf(-acc));
      else              thrB[gidx]   = acc;
    }
  }
}

// ---------------- Phase B: 256-step recurrent scan (R12 exact) --------------
// 256 WGs (batch = blockIdx&7, slice = blockIdx>>3), 256 threads, 1 neuron/thread.
// Exchange word: [tag8 | act12(odd) | act12(even)] — two neurons per dword,
// 12-bit fixed-point (quant err 1.2e-4; tags 1..255 per parity, no wrap).
// Data IS the flag. Reload-as-poll: re-issue the 16KB coherent (sc0 sc1)
// reload until every byte-tag matches t+1 — detection == data arrival,
// overlapped with publish latency. WAR safety (R6 induction): writer
// publishes tag t+3 into pw only after its verified t+2 reload of pw^1; a
// peer stores t+2 only after completing its verified t+1 reload of pw.
__global__ __launch_bounds__(256, 1) void scan_kernel(
    const float* __restrict__ cc, const int* __restrict__ ad_stored,
    const float* __restrict__ V0, const float* __restrict__ act0,
    const float* __restrict__ wconn, const float* __restrict__ decayB,
    const float* __restrict__ thrB,
    float* __restrict__ out, uint32_t* actbuf)
{
  const int tid = threadIdx.x;
  const int b   = blockIdx.x & 7;
  const int sl  = blockIdx.x >> 3;
  const int n    = sl * SLN + tid;
  const int gidx = b * NN + n;

  __shared__ uint32_t alds[NW];     // 16 KB: packed acts of batch b

  f32x4 w4[16];
  int   ad[KK];
  uint32_t mlo = 0, mhi = 0;
  {
    const f32x4* wr = reinterpret_cast<const f32x4*>(wconn + (size_t)gidx * KK);
    #pragma unroll
    for (int j = 0; j < 16; ++j) {
      f32x4 v = wr[j];
      w4[j] = v * (1.f / 4095.f);
    }
    const int4* ir = reinterpret_cast<const int4*>(ad_stored + (size_t)n * KK);
    #pragma unroll
    for (int j = 0; j < KK / 4; ++j) {
      int4 v = ir[j];
      ad[4*j+0] = v.x; ad[4*j+1] = v.y;
      ad[4*j+2] = v.z; ad[4*j+3] = v.w;
    }
    #pragma unroll
    for (int k = 0; k < 32; ++k) { mlo |= (uint32_t)(ad[k] & 1) << k;      ad[k] &= ~1; }
    #pragma unroll
    for (int k = 32; k < 64; ++k) { mhi |= (uint32_t)(ad[k] & 1) << (k-32); ad[k] &= ~1; }
  }
  float V     = V0[gidx];
  float dec   = decayB[gidx];
  float onemd = 1.f - dec;
  float thr   = thrB[gidx];

  // initial act into LDS, packed to the same 12-bit format
  for (int w = tid; w < NW; w += 256) {
    float a0 = act0[(size_t)b * NN + 2 * w];
    float a1 = act0[(size_t)b * NN + 2 * w + 1];
    uint32_t q0 = (uint32_t)__builtin_rintf(a0 * 4095.f);
    uint32_t q1 = (uint32_t)__builtin_rintf(a1 * 4095.f);
    alds[w] = (q1 << 12) | q0;
  }
  __syncthreads();

  float inj = cc[((size_t)b * TT) * DD + (n >> 2)];
  const char* abase = reinterpret_cast<const char*>(alds);

  for (int t = 0; t < TT; ++t) {
    float s0 = 0.f, s1 = 0.f, s2 = 0.f, s3 = 0.f;
    #pragma unroll
    for (int j = 0; j < 16; ++j) {
      uint32_t d0 = *reinterpret_cast<const uint32_t*>(abase + ad[4*j+0]);
      uint32_t d1 = *reinterpret_cast<const uint32_t*>(abase + ad[4*j+1]);
      uint32_t d2 = *reinterpret_cast<const uint32_t*>(abase + ad[4*j+2]);
      uint32_t d3 = *reinterpret_cast<const uint32_t*>(abase + ad[4*j+3]);
      uint32_t sh0, sh1, sh2, sh3;
      if (4*j+3 < 32) {
        sh0 = ((mlo >> (4*j+0)) & 1) * 12; sh1 = ((mlo >> (4*j+1)) & 1) * 12;
        sh2 = ((mlo >> (4*j+2)) & 1) * 12; sh3 = ((mlo >> (4*j+3)) & 1) * 12;
      } else {
        sh0 = ((mhi >> (4*j+0-32)) & 1) * 12; sh1 = ((mhi >> (4*j+1-32)) & 1) * 12;
        sh2 = ((mhi >> (4*j+2-32)) & 1) * 12; sh3 = ((mhi >> (4*j+3-32)) & 1) * 12;
      }
      s0 = fmaf((float)((d0 >> sh0) & 0xFFFu), w4[j].x, s0);
      s1 = fmaf((float)((d1 >> sh1) & 0xFFFu), w4[j].y, s1);
      s2 = fmaf((float)((d2 >> sh2) & 0xFFFu), w4[j].z, s2);
      s3 = fmaf((float)((d3 >> sh3) & 0xFFFu), w4[j].w, s3);
    }
    float recv = (s0 + s1) + (s2 + s3) + inj;
    V = dec * V + onemd * recv;
    float x = V - thr;
    float a = 1.f / (1.f + expf(-x));

    const int pw = t & 1;

    if (t != TT - 1) {
      uint32_t aq = (uint32_t)__builtin_rintf(a * 4095.f);
      uint32_t oq = (uint32_t)__shfl_xor((int)aq, 1);
      if ((tid & 1) == 0) {
        uint32_t word = ((uint32_t)(t + 1) << 24) | (oq << 12) | aq;
        uint32_t* dst = actbuf + (size_t)pw * (BS * NW) + (gidx >> 1);
        asm volatile("global_store_dword %0, %1, off sc0 sc1"
                     :: "v"(dst), "v"(word) : "memory");
      }
    }

    float p = a + __shfl_xor(a, 1);
    p = p + __shfl_xor(p, 2);
    if ((tid & 3) == 0)
      out[((size_t)b * TT + t) * DD + sl * 64 + (tid >> 2)] = 0.25f * p;

    if (t == TT - 1) break;

    inj = cc[((size_t)b * TT + t + 1) * DD + (n >> 2)];

    const uint32_t* src = actbuf + (size_t)pw * (BS * NW) + (size_t)b * NW;
    const uint32_t tag = (uint32_t)(t + 1);
    u32x4 vals[4];
    for (;;) {
      #pragma unroll
      for (int j = 0; j < 4; ++j) {
        const uint32_t* p4 = src + (tid << 2) + (j << 10);
        asm volatile("global_load_dwordx4 %0, %1, off sc0 sc1"
                     : "=v"(vals[j]) : "v"(p4));
      }
      asm volatile("s_waitcnt vmcnt(0)" ::: "memory");
      uint32_t bad = 0;
      #pragma unroll
      for (int j = 0; j < 4; ++j) {
        bad |= (vals[j].x >> 24) ^ tag;
        bad |= (vals[j].y >> 24) ^ tag;
        bad |= (vals[j].z >> 24) ^ tag;
        bad |= (vals[j].w >> 24) ^ tag;
      }
      if (bad == 0) break;
    }
    {
      u32x4* dst = reinterpret_cast<u32x4*>(alds);
      #pragma unroll
      for (int j = 0; j < 4; ++j) dst[tid + j * 256] = vals[j];
    }
    __syncthreads();
  }
}

extern "C" void kernel_launch(void* const* d_in, const int* in_sizes, int n_in,
                              void* d_out, int out_size, void* d_ws, size_t ws_size,
                              hipStream_t stream)
{
  const float* cc   = (const float*)d_in[0];
  const float* w1   = (const float*)d_in[1];
  const float* b1   = (const float*)d_in[2];
  const float* w2   = (const float*)d_in[3];
  const float* b2   = (const float*)d_in[4];
  const int*   conn = (const int*)d_in[5];
  const float* nid  = (const float*)d_in[6];
  const float* V0   = (const float*)d_in[7];
  const float* act0 = (const float*)d_in[8];
  const float* heb0 = (const float*)d_in[9];
  const float* dec0 = (const float*)d_in[10];
  const float* thr0 = (const float*)d_in[11];
  float* out = (float*)d_out;

  char* ws = (char*)d_ws;
  float*         wconn  = (float*)ws;                                   // 16 MB
  float*         decayB = (float*)(ws + (size_t)BS * NN * KK * 4);      // 256 KB
  float*         thrB   = decayB + BS * NN;                             // 256 KB
  uint32_t*      actbuf = (uint32_t*)(thrB + BS * NN);                  // 2*8*4096 dw
  int*           ad_st  = (int*)(actbuf + 2 * BS * NW);                 // 2 MB
  unsigned char* inv2   = (unsigned char*)(ad_st + (size_t)NN * KK);    // 512 KB

  // zero tags every launch (replay-deterministic; first poll expects tag 1)
  hipMemsetAsync(actbuf, 0, 2 * BS * NW * sizeof(uint32_t), stream);

  prep_kernel<<<dim3(NN * KK / 256), 256, 0, stream>>>(conn, ad_st, inv2);
  modulator_kernel<<<dim3(GG), 256, 0, stream>>>(w1, b1, w2, b2, act0, heb0, dec0,
                                                 thr0, nid, inv2, wconn, decayB, thrB);
  scan_kernel<<<dim3(BS * NSL), 256, 0, stream>>>(cc, ad_st, V0, act0, wconn,
                                                  decayB, thrB, out, actbuf);
}